// Round 8
// baseline (122.028 us; speedup 1.0000x reference)
//
#include <hip/hip_runtime.h>

// LGNLayer: 2-kernel structure.
//   k_retina:  256MB stream matvec, 1 wave = 1 row; also resets the block counter.
//   k_lgn_wta: 64MB read + 64MB copy-out fused matvec (1 wave = 1 row), then the
//              LAST block to finish (device-scope counter) runs the WTA tail:
//              argmax + threshold vector + winner-row update.
// Outputs concatenated: new_firing[8192], lgn_act[2048], lgn_weights[2048*8192], lgn_threshold[2048].

constexpr int N_RET = 8192;
constexpr int N_LGN = 2048;
constexpr float ETA = 0.1f;
constexpr float MU_WTS = 2.5f;
constexpr int LGN_BLOCKS = N_LGN / 4;   // 512

typedef float vf4 __attribute__((ext_vector_type(4)));

__device__ __forceinline__ vf4 ntload4(const float* p) {
    return __builtin_nontemporal_load(reinterpret_cast<const vf4*>(p));
}
__device__ __forceinline__ void ntstore4(float* p, vf4 v) {
    __builtin_nontemporal_store(v, reinterpret_cast<vf4*>(p));
}
__device__ __forceinline__ vf4 ld4(const float* p) {
    return *reinterpret_cast<const vf4*>(p);
}
__device__ __forceinline__ void st4(float* p, vf4 v) {
    *reinterpret_cast<vf4*>(p) = v;
}

// ---------- K1: new_firing = (retina_weights @ is_firing > retina_threshold) ----------
// 1 wave per row; 4 rows per 256-thread block; no __syncthreads, no LDS.
__global__ __launch_bounds__(256) void k_retina(
    const float* __restrict__ rw, const float* __restrict__ rthr,
    const float* __restrict__ firing, float* __restrict__ new_firing,
    unsigned int* __restrict__ counter)
{
    const int t = threadIdx.x;
    if (blockIdx.x == 0 && t == 0) *counter = 0u;   // visible to k_lgn_wta via dispatch barrier
    const int lane = t & 63, wv = t >> 6;
    const int row = blockIdx.x * 4 + wv;
    const float* __restrict__ wr = rw + (size_t)row * N_RET;
    vf4 acc = (vf4)(0.0f);
#pragma unroll 8
    for (int it = 0; it < (N_RET / 4) / 64; ++it) {   // 32 iterations
        const int j = (lane + it * 64) * 4;
        acc += ntload4(wr + j) * ld4(firing + j);      // weights stream; firing L1/L2-hot
    }
    float v = (acc.x + acc.y) + (acc.z + acc.w);
#pragma unroll
    for (int off = 32; off > 0; off >>= 1) v += __shfl_down(v, off, 64);
    if (lane == 0) new_firing[row] = (v > rthr[row]) ? 1.0f : 0.0f;
}

// ---------- K2: lgn matvec + relu + fused copy-out, then last-block WTA tail ----------
__global__ __launch_bounds__(256) void k_lgn_wta(
    const float* __restrict__ lw, const float* __restrict__ firing,
    const float* __restrict__ lthr,
    float* __restrict__ lgn_act, float* __restrict__ w_out,
    float* __restrict__ thr_out, unsigned int* __restrict__ counter)
{
    const int t = threadIdx.x;
    const int lane = t & 63, wv = t >> 6;

    // --- per-wave row matvec + copy ---
    {
        const int row = blockIdx.x * 4 + wv;
        const float* __restrict__ wr = lw + (size_t)row * N_RET;
        float* __restrict__ wo = w_out + (size_t)row * N_RET;
        vf4 acc = (vf4)(0.0f);
#pragma unroll 8
        for (int it = 0; it < (N_RET / 4) / 64; ++it) {   // 32 iterations
            const int j = (lane + it * 64) * 4;
            const vf4 w = ntload4(wr + j);
            const vf4 f = ld4(firing + j);
            ntstore4(wo + j, w);                           // fused copy, streaming store
            acc += w * f;
        }
        float v = (acc.x + acc.y) + (acc.z + acc.w);
#pragma unroll
        for (int off = 32; off > 0; off >>= 1) v += __shfl_down(v, off, 64);
        if (lane == 0) lgn_act[row] = fmaxf(v, 0.0f);
    }

    // --- elect the closing block (release stores, acq_rel RMW, agent scope) ---
    __shared__ bool s_last;
    __syncthreads();
    if (t == 0) {
        __threadfence();   // release: publish lgn_act + w_out stores to coherence point
        const unsigned old = __hip_atomic_fetch_add(counter, 1u,
                                                    __ATOMIC_ACQ_REL,
                                                    __HIP_MEMORY_SCOPE_AGENT);
        s_last = (old == (unsigned)(gridDim.x - 1));
    }
    __syncthreads();
    if (!s_last) return;

    // ================= WTA tail (one block, 256 threads) =================
    __shared__ float sv[4];
    __shared__ int si[4];
    __shared__ float s_val, s_mean;
    __shared__ int s_idx;

    // argmax(act) with first-index tie-break; acquire loads bypass stale local L2
    float bv = -1.0f;      // act >= 0 always
    int bi = 0x40000000;
#pragma unroll
    for (int k = 0; k < N_LGN / 256; ++k) {   // 8 iterations, ascending j per thread
        const int j = t + k * 256;
        const float aj = __hip_atomic_load(&lgn_act[j], __ATOMIC_ACQUIRE,
                                           __HIP_MEMORY_SCOPE_AGENT);
        const float a = fmaxf(aj - lthr[j], 0.0f);
        if (a > bv) { bv = a; bi = j; }       // strict > keeps earliest index
    }
#pragma unroll
    for (int off = 32; off > 0; off >>= 1) {
        const float ov = __shfl_down(bv, off, 64);
        const int oi = __shfl_down(bi, off, 64);
        if (ov > bv || (ov == bv && oi < bi)) { bv = ov; bi = oi; }
    }
    if (lane == 0) { sv[wv] = bv; si[wv] = bi; }
    __syncthreads();
    if (t == 0) {
        float v = sv[0]; int i = si[0];
#pragma unroll
        for (int k = 1; k < 4; ++k)
            if (sv[k] > v || (sv[k] == v && si[k] < i)) { v = sv[k]; i = si[k]; }
        s_val = v; s_idx = i;
    }
    __syncthreads();
    const float val = s_val;
    const int idx = s_idx;

    // threshold output (winner patched inline)
#pragma unroll
    for (int k = 0; k < N_LGN / 256; ++k) {
        const int j = t + k * 256;
        float tv = lthr[j];
        if (val > 0.0f && j == idx) tv += 0.005f * val;
        thr_out[j] = tv;
    }
    if (!(val > 0.0f)) return;   // uniform: no weight update

    // winner row: x = (w + a) + a; row = x / mean(x) * MU_WTS
    const float* __restrict__ wr = lw + (size_t)idx * N_RET;
    float* __restrict__ wo = w_out + (size_t)idx * N_RET;
    const float av = 0.5f * (ETA * val);   // a = av * f, f in {0,1}

    vf4 x[(N_RET / 4) / 256];   // 8 x vf4 = 32 VGPRs
    float part = 0.0f;
#pragma unroll
    for (int k = 0; k < (N_RET / 4) / 256; ++k) {
        const int j = (t + k * 256) * 4;
        const vf4 w = ld4(wr + j);
        const vf4 f = ld4(firing + j);
        vf4 v = (w + av * f) + av * f;     // two half-additions, like ref
        x[k] = v;
        part += (v.x + v.y) + (v.z + v.w);
    }
#pragma unroll
    for (int off = 32; off > 0; off >>= 1) part += __shfl_down(part, off, 64);
    if (lane == 0) sv[wv] = part;          // reuse sv
    __syncthreads();
    if (t == 0) s_mean = ((sv[0] + sv[1]) + (sv[2] + sv[3])) / (float)N_RET;
    __syncthreads();
    const float m = s_mean;
#pragma unroll
    for (int k = 0; k < (N_RET / 4) / 256; ++k) {
        const int j = (t + k * 256) * 4;
        st4(wo + j, x[k] / m * MU_WTS);
    }
}

extern "C" void kernel_launch(void* const* d_in, const int* in_sizes, int n_in,
                              void* d_out, int out_size, void* d_ws, size_t ws_size,
                              hipStream_t stream)
{
    const float* rw   = (const float*)d_in[0];   // retina_weights [8192, 8192]
    const float* rthr = (const float*)d_in[1];   // retina_threshold [8192]
    const float* lw   = (const float*)d_in[2];   // lgn_weights [2048, 8192]
    const float* lthr = (const float*)d_in[3];   // lgn_threshold [2048]
    const float* fir  = (const float*)d_in[4];   // is_firing [8192]

    float* out   = (float*)d_out;
    float* o_fir = out;                                         // [8192]
    float* o_act = out + N_RET;                                 // [2048]
    float* o_w   = out + N_RET + N_LGN;                         // [2048*8192]
    float* o_thr = o_w + (size_t)N_LGN * N_RET;                 // [2048]
    unsigned int* counter = (unsigned int*)d_ws;

    hipLaunchKernelGGL(k_retina,  dim3(N_RET / 4), dim3(256), 0, stream,
                       rw, rthr, fir, o_fir, counter);
    hipLaunchKernelGGL(k_lgn_wta, dim3(LGN_BLOCKS), dim3(256), 0, stream,
                       lw, o_fir, lthr, o_act, o_w, o_thr, counter);
}

// Round 9
// 76.292 us; speedup vs baseline: 1.5995x; 1.5995x over previous
//
#include <hip/hip_runtime.h>

// LGNLayer: 3-kernel structure (R7) with occupancy-fixed k_lgn.
//   k_retina: 256MB stream matvec, 1 wave = 1 row, 2048 blocks (8/CU, 32 waves/CU).
//   k_lgn:    64MB read + 64MB copy-out fused; 2 waves = 1 row (half-row each),
//             1024 blocks (4/CU, 16 waves/CU) - was 512 blocks / 8 waves/CU in R7.
//   k_wta:    argmax + threshold + winner-row update (single block, 1024 thr).
// Outputs concatenated: new_firing[8192], lgn_act[2048], lgn_weights[2048*8192], lgn_threshold[2048].

constexpr int N_RET = 8192;
constexpr int N_LGN = 2048;
constexpr float ETA = 0.1f;
constexpr float MU_WTS = 2.5f;

typedef float vf4 __attribute__((ext_vector_type(4)));

__device__ __forceinline__ vf4 ntload4(const float* p) {
    return __builtin_nontemporal_load(reinterpret_cast<const vf4*>(p));
}
__device__ __forceinline__ void ntstore4(float* p, vf4 v) {
    __builtin_nontemporal_store(v, reinterpret_cast<vf4*>(p));
}
__device__ __forceinline__ vf4 ld4(const float* p) {
    return *reinterpret_cast<const vf4*>(p);
}
__device__ __forceinline__ void st4(float* p, vf4 v) {
    *reinterpret_cast<vf4*>(p) = v;
}

// ---------- K1: new_firing = (retina_weights @ is_firing > retina_threshold) ----------
// 1 wave per row; 4 rows per 256-thread block; no __syncthreads, no LDS.
__global__ __launch_bounds__(256) void k_retina(
    const float* __restrict__ rw, const float* __restrict__ rthr,
    const float* __restrict__ firing, float* __restrict__ new_firing)
{
    const int t = threadIdx.x;
    const int lane = t & 63, wv = t >> 6;
    const int row = blockIdx.x * 4 + wv;
    const float* __restrict__ wr = rw + (size_t)row * N_RET;
    vf4 acc = (vf4)(0.0f);
#pragma unroll 8
    for (int it = 0; it < (N_RET / 4) / 64; ++it) {   // 32 iterations
        const int j = (lane + it * 64) * 4;
        acc += ntload4(wr + j) * ld4(firing + j);      // weights stream; firing L1/L2-hot
    }
    float v = (acc.x + acc.y) + (acc.z + acc.w);
#pragma unroll
    for (int off = 32; off > 0; off >>= 1) v += __shfl_down(v, off, 64);
    if (lane == 0) new_firing[row] = (v > rthr[row]) ? 1.0f : 0.0f;
}

// ---------- K2: lgn_act = relu(lgn_weights @ new_firing); fused weights copy-out ----------
// 2 waves per row (half-row each); 2 rows per 256-thread block; 1024 blocks.
__global__ __launch_bounds__(256) void k_lgn(
    const float* __restrict__ lw, const float* __restrict__ firing,
    float* __restrict__ lgn_act, float* __restrict__ w_out)
{
    const int t = threadIdx.x;
    const int lane = t & 63, wv = t >> 6;            // 4 waves
    const int row = blockIdx.x * 2 + (wv >> 1);      // 2 rows per block
    const int half = wv & 1;                         // which half-row this wave owns
    const float* __restrict__ wr = lw + (size_t)row * N_RET + half * (N_RET / 2);
    float* __restrict__ wo = w_out + (size_t)row * N_RET + half * (N_RET / 2);
    const float* __restrict__ fh = firing + half * (N_RET / 2);

    vf4 acc = (vf4)(0.0f);
#pragma unroll 8
    for (int it = 0; it < (N_RET / 8) / 64; ++it) {   // 16 iterations (4096 floats/wave)
        const int j = (lane + it * 64) * 4;
        const vf4 w = ntload4(wr + j);
        const vf4 f = ld4(fh + j);
        ntstore4(wo + j, w);                           // fused copy, streaming store
        acc += w * f;
    }
    float v = (acc.x + acc.y) + (acc.z + acc.w);
#pragma unroll
    for (int off = 32; off > 0; off >>= 1) v += __shfl_down(v, off, 64);
    __shared__ float s[4];
    if (lane == 0) s[wv] = v;
    __syncthreads();
    if (t == 0) {
        lgn_act[row]     = fmaxf(s[0] + s[1], 0.0f);
        lgn_act[row + 1] = fmaxf(s[2] + s[3], 0.0f);
    }
}

// ---------- K3: argmax + threshold output + winner-row update (single block, 1024 thr) ----------
__global__ __launch_bounds__(1024) void k_wta(
    const float* __restrict__ lgn_act, const float* __restrict__ lthr,
    const float* __restrict__ lw, const float* __restrict__ firing,
    float* __restrict__ thr_out, float* __restrict__ w_out)
{
    const int t = threadIdx.x;
    const int lane = t & 63, wv = t >> 6;
    __shared__ float sv[16];
    __shared__ int si[16];
    __shared__ float s_val, s_mean;
    __shared__ int s_idx;

    // argmax(act) with first-index tie-break (ascending scan, strict >)
    float bv = -1.0f;      // act >= 0 always
    int bi = 0x40000000;
#pragma unroll
    for (int k = 0; k < N_LGN / 1024; ++k) {   // 2 iterations, ascending j per thread
        const int j = t + k * 1024;
        const float a = fmaxf(lgn_act[j] - lthr[j], 0.0f);
        if (a > bv) { bv = a; bi = j; }
    }
#pragma unroll
    for (int off = 32; off > 0; off >>= 1) {
        const float ov = __shfl_down(bv, off, 64);
        const int oi = __shfl_down(bi, off, 64);
        if (ov > bv || (ov == bv && oi < bi)) { bv = ov; bi = oi; }
    }
    if (lane == 0) { sv[wv] = bv; si[wv] = bi; }
    __syncthreads();
    if (t == 0) {
        float v = sv[0]; int i = si[0];
#pragma unroll
        for (int k = 1; k < 16; ++k)
            if (sv[k] > v || (sv[k] == v && si[k] < i)) { v = sv[k]; i = si[k]; }
        s_val = v; s_idx = i;
    }
    __syncthreads();
    const float val = s_val;
    const int idx = s_idx;

    // threshold output (winner patched inline)
#pragma unroll
    for (int k = 0; k < N_LGN / 1024; ++k) {
        const int j = t + k * 1024;
        float tv = lthr[j];
        if (val > 0.0f && j == idx) tv += 0.005f * val;
        thr_out[j] = tv;
    }
    if (!(val > 0.0f)) return;   // uniform: no weight update

    // winner row: x = (w + a) + a; row = x / mean(x) * MU_WTS
    const float* __restrict__ wr = lw + (size_t)idx * N_RET;
    float* __restrict__ wo = w_out + (size_t)idx * N_RET;
    const float av = 0.5f * (ETA * val);   // a = av * f, f in {0,1}

    vf4 x[2];
    float part = 0.0f;
#pragma unroll
    for (int k = 0; k < (N_RET / 4) / 1024; ++k) {   // 2 iterations
        const int j = (t + k * 1024) * 4;
        const vf4 w = ld4(wr + j);
        const vf4 f = ld4(firing + j);
        vf4 v = (w + av * f) + av * f;               // two half-additions, like ref
        x[k] = v;
        part += (v.x + v.y) + (v.z + v.w);
    }
#pragma unroll
    for (int off = 32; off > 0; off >>= 1) part += __shfl_down(part, off, 64);
    __shared__ float red[16];
    if (lane == 0) red[wv] = part;
    __syncthreads();
    if (t == 0) {
        float sum = 0.0f;
#pragma unroll
        for (int k = 0; k < 16; ++k) sum += red[k];
        s_mean = sum / (float)N_RET;
    }
    __syncthreads();
    const float m = s_mean;
#pragma unroll
    for (int k = 0; k < (N_RET / 4) / 1024; ++k) {
        const int j = (t + k * 1024) * 4;
        st4(wo + j, x[k] / m * MU_WTS);
    }
}

extern "C" void kernel_launch(void* const* d_in, const int* in_sizes, int n_in,
                              void* d_out, int out_size, void* d_ws, size_t ws_size,
                              hipStream_t stream)
{
    const float* rw   = (const float*)d_in[0];   // retina_weights [8192, 8192]
    const float* rthr = (const float*)d_in[1];   // retina_threshold [8192]
    const float* lw   = (const float*)d_in[2];   // lgn_weights [2048, 8192]
    const float* lthr = (const float*)d_in[3];   // lgn_threshold [2048]
    const float* fir  = (const float*)d_in[4];   // is_firing [8192]

    float* out   = (float*)d_out;
    float* o_fir = out;                                         // [8192]
    float* o_act = out + N_RET;                                 // [2048]
    float* o_w   = out + N_RET + N_LGN;                         // [2048*8192]
    float* o_thr = o_w + (size_t)N_LGN * N_RET;                 // [2048]

    hipLaunchKernelGGL(k_retina, dim3(N_RET / 4), dim3(256),  0, stream, rw, rthr, fir, o_fir);
    hipLaunchKernelGGL(k_lgn,    dim3(N_LGN / 2), dim3(256),  0, stream, lw, o_fir, o_act, o_w);
    hipLaunchKernelGGL(k_wta,    dim3(1),         dim3(1024), 0, stream, o_act, lthr, lw, o_fir, o_thr, o_w);
}

// Round 10
// 74.375 us; speedup vs baseline: 1.6407x; 1.0258x over previous
//
#include <hip/hip_runtime.h>

// LGNLayer: 3-kernel structure, R7 matvecs + k_wta slimmed via per-block argmax
// candidates (distinct-address plain stores — NO same-address atomics, R4 lesson).
//   k_retina: 256MB stream matvec, 1 wave = 1 row, 2048 blocks.
//   k_lgn:    64MB read + 64MB copy-out fused, 1 wave = 1 row, 512 blocks; also
//             writes thr_out[row] (non-winner value) and ws[bid] = packed block
//             argmax candidate (val bits << 32 | ~row  -> max = first-index argmax).
//   k_wta:    reduce 512 candidates + patch thr_out[idx] + winner-row update.
// Outputs concatenated: new_firing[8192], lgn_act[2048], lgn_weights[2048*8192], lgn_threshold[2048].

constexpr int N_RET = 8192;
constexpr int N_LGN = 2048;
constexpr float ETA = 0.1f;
constexpr float MU_WTS = 2.5f;
constexpr int LGN_BLOCKS = N_LGN / 4;   // 512

typedef float vf4 __attribute__((ext_vector_type(4)));
typedef unsigned long long u64;

__device__ __forceinline__ vf4 ntload4(const float* p) {
    return __builtin_nontemporal_load(reinterpret_cast<const vf4*>(p));
}
__device__ __forceinline__ void ntstore4(float* p, vf4 v) {
    __builtin_nontemporal_store(v, reinterpret_cast<vf4*>(p));
}
__device__ __forceinline__ vf4 ld4(const float* p) {
    return *reinterpret_cast<const vf4*>(p);
}
__device__ __forceinline__ void st4(float* p, vf4 v) {
    *reinterpret_cast<vf4*>(p) = v;
}

// ---------- K1: new_firing = (retina_weights @ is_firing > retina_threshold) ----------
// 1 wave per row; 4 rows per 256-thread block; no __syncthreads, no LDS.
__global__ __launch_bounds__(256) void k_retina(
    const float* __restrict__ rw, const float* __restrict__ rthr,
    const float* __restrict__ firing, float* __restrict__ new_firing)
{
    const int t = threadIdx.x;
    const int lane = t & 63, wv = t >> 6;
    const int row = blockIdx.x * 4 + wv;
    const float* __restrict__ wr = rw + (size_t)row * N_RET;
    vf4 acc = (vf4)(0.0f);
#pragma unroll 8
    for (int it = 0; it < (N_RET / 4) / 64; ++it) {   // 32 iterations
        const int j = (lane + it * 64) * 4;
        acc += ntload4(wr + j) * ld4(firing + j);      // weights stream; firing L1/L2-hot
    }
    float v = (acc.x + acc.y) + (acc.z + acc.w);
#pragma unroll
    for (int off = 32; off > 0; off >>= 1) v += __shfl_down(v, off, 64);
    if (lane == 0) new_firing[row] = (v > rthr[row]) ? 1.0f : 0.0f;
}

// ---------- K2: lgn matvec + relu + fused copy-out + thr passthrough + argmax cand ----------
// 1 wave per row; 4 rows per block; 512 blocks.
__global__ __launch_bounds__(256) void k_lgn(
    const float* __restrict__ lw, const float* __restrict__ firing,
    const float* __restrict__ lthr,
    float* __restrict__ lgn_act, float* __restrict__ w_out,
    float* __restrict__ thr_out, u64* __restrict__ ws_cand)
{
    const int t = threadIdx.x;
    const int lane = t & 63, wv = t >> 6;
    const int row = blockIdx.x * 4 + wv;
    const float* __restrict__ wr = lw + (size_t)row * N_RET;
    float* __restrict__ wo = w_out + (size_t)row * N_RET;
    vf4 acc = (vf4)(0.0f);
#pragma unroll 8
    for (int it = 0; it < (N_RET / 4) / 64; ++it) {   // 32 iterations
        const int j = (lane + it * 64) * 4;
        const vf4 w = ntload4(wr + j);
        const vf4 f = ld4(firing + j);
        ntstore4(wo + j, w);                           // fused copy, streaming store
        acc += w * f;
    }
    float v = (acc.x + acc.y) + (acc.z + acc.w);
#pragma unroll
    for (int off = 32; off > 0; off >>= 1) v += __shfl_down(v, off, 64);

    __shared__ u64 cand[4];
    if (lane == 0) {
        const float act = fmaxf(v, 0.0f);
        lgn_act[row] = act;
        const float thr = lthr[row];
        thr_out[row] = thr;                            // non-winner value; k_wta patches winner
        const float a = fmaxf(act - thr, 0.0f);
        // pack: val bits high (monotone for val>=0), ~row low (max -> lowest row on ties)
        cand[wv] = ((u64)__float_as_uint(a) << 32) | (unsigned)(~row);
    }
    __syncthreads();
    if (t == 0) {
        u64 m = cand[0];
#pragma unroll
        for (int k = 1; k < 4; ++k) m = (cand[k] > m) ? cand[k] : m;
        ws_cand[blockIdx.x] = m;                       // distinct address per block: no contention
    }
}

// ---------- K3: reduce 512 candidates + thr patch + winner-row update ----------
__global__ __launch_bounds__(1024) void k_wta(
    const float* __restrict__ lthr,
    const float* __restrict__ lw, const float* __restrict__ firing,
    float* __restrict__ thr_out, float* __restrict__ w_out,
    const u64* __restrict__ ws_cand)
{
    const int t = threadIdx.x;
    const int lane = t & 63, wv = t >> 6;
    __shared__ u64 sm[16];
    __shared__ float s_val, s_mean;
    __shared__ int s_idx;

    // max over 512 packed candidates (u64 max == argmax with first-index ties)
    u64 m = (t < LGN_BLOCKS) ? ws_cand[t] : 0ULL;
#pragma unroll
    for (int off = 32; off > 0; off >>= 1) {
        const u64 o = __shfl_down(m, off, 64);
        m = (o > m) ? o : m;
    }
    if (lane == 0) sm[wv] = m;
    __syncthreads();
    if (t == 0) {
        u64 mm = sm[0];
#pragma unroll
        for (int k = 1; k < 16; ++k) mm = (sm[k] > mm) ? sm[k] : mm;
        s_val = __uint_as_float((unsigned)(mm >> 32));
        s_idx = (int)(~(unsigned)(mm & 0xFFFFFFFFu));
    }
    __syncthreads();
    const float val = s_val;
    const int idx = s_idx;
    if (!(val > 0.0f)) return;   // uniform: thr_out already correct, no weight update

    if (t == 0) thr_out[idx] = lthr[idx] + 0.005f * val;

    // winner row: x = (w + a) + a; row = x / mean(x) * MU_WTS
    const float* __restrict__ wr = lw + (size_t)idx * N_RET;
    float* __restrict__ wo = w_out + (size_t)idx * N_RET;
    const float av = 0.5f * (ETA * val);   // a = av * f, f in {0,1}

    vf4 x[2];
    float part = 0.0f;
#pragma unroll
    for (int k = 0; k < (N_RET / 4) / 1024; ++k) {   // 2 iterations
        const int j = (t + k * 1024) * 4;
        const vf4 w = ld4(wr + j);
        const vf4 f = ld4(firing + j);
        vf4 v = (w + av * f) + av * f;               // two half-additions, like ref
        x[k] = v;
        part += (v.x + v.y) + (v.z + v.w);
    }
#pragma unroll
    for (int off = 32; off > 0; off >>= 1) part += __shfl_down(part, off, 64);
    __shared__ float red[16];
    if (lane == 0) red[wv] = part;
    __syncthreads();
    if (t == 0) {
        float sum = 0.0f;
#pragma unroll
        for (int k = 0; k < 16; ++k) sum += red[k];
        s_mean = sum / (float)N_RET;
    }
    __syncthreads();
    const float mn = s_mean;
#pragma unroll
    for (int k = 0; k < (N_RET / 4) / 1024; ++k) {
        const int j = (t + k * 1024) * 4;
        st4(wo + j, x[k] / mn * MU_WTS);
    }
}

extern "C" void kernel_launch(void* const* d_in, const int* in_sizes, int n_in,
                              void* d_out, int out_size, void* d_ws, size_t ws_size,
                              hipStream_t stream)
{
    const float* rw   = (const float*)d_in[0];   // retina_weights [8192, 8192]
    const float* rthr = (const float*)d_in[1];   // retina_threshold [8192]
    const float* lw   = (const float*)d_in[2];   // lgn_weights [2048, 8192]
    const float* lthr = (const float*)d_in[3];   // lgn_threshold [2048]
    const float* fir  = (const float*)d_in[4];   // is_firing [8192]

    float* out   = (float*)d_out;
    float* o_fir = out;                                         // [8192]
    float* o_act = out + N_RET;                                 // [2048]
    float* o_w   = out + N_RET + N_LGN;                         // [2048*8192]
    float* o_thr = o_w + (size_t)N_LGN * N_RET;                 // [2048]
    u64* ws_cand = (u64*)d_ws;                                  // [512] block candidates

    hipLaunchKernelGGL(k_retina, dim3(N_RET / 4),  dim3(256),  0, stream, rw, rthr, fir, o_fir);
    hipLaunchKernelGGL(k_lgn,    dim3(LGN_BLOCKS), dim3(256),  0, stream,
                       lw, o_fir, lthr, o_act, o_w, o_thr, ws_cand);
    hipLaunchKernelGGL(k_wta,    dim3(1),          dim3(1024), 0, stream,
                       lthr, lw, o_fir, o_thr, o_w, ws_cand);
}